// Round 6
// baseline (205.346 us; speedup 1.0000x reference)
//
#include <hip/hip_runtime.h>

// Problem constants
#define TT     2048
#define NB     32
#define NL     10
#define NU     64
#define TTILE  64
#define NTTILE 32          // chunks per b (one per block after in-block fold)
#define NW     20          // iterated-sum words per (b,chunk,u)
#define DT2    145         // d-tile row stride (floats), odd -> conflict-light

// d_ws layout: L [b][c(32)][w(20)][u(64)] fp32 @0 (5,242,880 B); counters @ L end (128 int)
#define CTR_OFF (NB * NTTILE * NW * NU * 4)

// LDS float offsets (total 11,972 floats = 47,888 B -> 3 blocks/CU)
#define XS_OFF   0        // [4096]  raw x tile rows t0-1..t0+63 (or 0..63 shifted)
#define A_OFF    4096     // [2048]  A fragments (4096 bf16)
#define B_OFF    6144     // [5120]  B fragments (10240 bf16)
#define W0_OFF   11264    // [64]    word-0 partials
#define FLAG_OFF 11328    // [1]     winner flag (int)
#define FB_OFF   11330    // [640]   fold tree buf [2][20][16]
// dtile aliases [0, 9280) after MFMA (xs+A+part of B are dead then)

typedef __attribute__((ext_vector_type(8))) short short8v;   // 8 bf16
typedef __attribute__((ext_vector_type(4))) float float4v;   // MFMA C/D
typedef __attribute__((address_space(3))) char lds_char;
typedef __attribute__((address_space(1))) const char g_char;

__device__ inline short f2bf(float f) {   // RNE float->bf16 raw bits
    unsigned u = __float_as_uint(f);
    u += 0x7fffu + ((u >> 16) & 1u);
    return (short)(u >> 16);
}

// ---- Chen composition (full 20-word alphabet), C = A(earlier) ∘ B(later) ----
// 0:(0) | 1:(1) 2:(2) 3:(12) | 4:(3) 5:(4) 6:(5) 7:(34) 8:(45) 9:(345)
// 10:(6) 11:(7) 12:(8) 13:(9) 14:(67) 15:(78) 16:(89) 17:(678) 18:(789) 19:(6789)
__device__ inline void chen_combine(const float* A, const float* B, float* C) {
    C[0]  = A[0] + B[0];
    C[1]  = A[1] + B[1];
    C[2]  = A[2] + B[2];
    C[3]  = A[3] + A[1]*B[2] + B[3];
    C[4]  = A[4] + B[4];
    C[5]  = A[5] + B[5];
    C[6]  = A[6] + B[6];
    C[7]  = A[7] + A[4]*B[5] + B[7];
    C[8]  = A[8] + A[5]*B[6] + B[8];
    C[9]  = A[9] + A[7]*B[6] + A[4]*B[8] + B[9];
    C[10] = A[10] + B[10];
    C[11] = A[11] + B[11];
    C[12] = A[12] + B[12];
    C[13] = A[13] + B[13];
    C[14] = A[14] + A[10]*B[11] + B[14];
    C[15] = A[15] + A[11]*B[12] + B[15];
    C[16] = A[16] + A[12]*B[13] + B[16];
    C[17] = A[17] + A[14]*B[12] + A[10]*B[15] + B[17];
    C[18] = A[18] + A[15]*B[13] + A[11]*B[16] + B[18];
    C[19] = A[19] + A[17]*B[13] + A[14]*B[16] + A[10]*B[18] + B[19];
}

// ---- chain-local Chen combiners ----
struct Chen1 {  // S0=(1) S1=(2) S2=(12)
    __device__ void operator()(const float* A, const float* B, float* C) const {
        C[2] = A[2] + A[0]*B[1] + B[2];
        C[0] = A[0] + B[0];  C[1] = A[1] + B[1];
    }
};
struct Chen2 {  // S0=(3) S1=(4) S2=(5) S3=(34) S4=(45) S5=(345)
    __device__ void operator()(const float* A, const float* B, float* C) const {
        C[5] = A[5] + A[3]*B[2] + A[0]*B[4] + B[5];
        C[3] = A[3] + A[0]*B[1] + B[3];
        C[4] = A[4] + A[1]*B[2] + B[4];
        C[0] = A[0] + B[0];  C[1] = A[1] + B[1];  C[2] = A[2] + B[2];
    }
};
struct Chen3 {  // S0..3=(6)(7)(8)(9) S4=(67) S5=(78) S6=(89) S7=(678) S8=(789) S9=(6789)
    __device__ void operator()(const float* A, const float* B, float* C) const {
        C[9] = A[9] + A[7]*B[3] + A[4]*B[6] + A[0]*B[8] + B[9];
        C[7] = A[7] + A[4]*B[2] + A[0]*B[5] + B[7];
        C[8] = A[8] + A[5]*B[3] + A[1]*B[6] + B[8];
        C[4] = A[4] + A[0]*B[1] + B[4];
        C[5] = A[5] + A[1]*B[2] + B[5];
        C[6] = A[6] + A[2]*B[3] + B[6];
        C[0] = A[0] + B[0];  C[1] = A[1] + B[1];
        C[2] = A[2] + B[2];  C[3] = A[3] + B[3];
    }
};
struct Chen20 {
    __device__ void operator()(const float* A, const float* B, float* C) const {
        chen_combine(A, B, C);
    }
};

// Cross-lane fold of 4 t-ordered groups (grp = lane>>4) via xor-16/32 tree.
// After return every lane holds the full combined value.
template <int N, typename CH>
__device__ inline void wave_fold(float* S, int grp, CH chen) {
    float O[N], A[N], Bv[N], C[N];
#pragma unroll
    for (int w = 0; w < N; ++w) O[w] = __shfl_xor(S[w], 16);
    {
        const bool e = (grp & 1) == 0;
#pragma unroll
        for (int w = 0; w < N; ++w) { A[w] = e ? S[w] : O[w]; Bv[w] = e ? O[w] : S[w]; }
        chen(A, Bv, C);
    }
#pragma unroll
    for (int w = 0; w < N; ++w) O[w] = __shfl_xor(C[w], 32);
    {
        const bool e = (grp & 2) == 0;
#pragma unroll
        for (int w = 0; w < N; ++w) { A[w] = e ? C[w] : O[w]; Bv[w] = e ? O[w] : C[w]; }
        chen(A, Bv, S);
    }
}

// Fused kernel: stage x/K -> build bf16 fragments -> MFMA d = dX*K -> chain scans
// -> in-block Chen fold (64 t-steps -> 1 chunk) -> write 20 words -> last block
// per (b,uq) folds all 32 chunks and writes the output.
__global__ __launch_bounds__(256, 3)
void k_fused(const float* __restrict__ x, const float* __restrict__ K,
             float* __restrict__ L, unsigned* __restrict__ ctr,
             float* __restrict__ out) {
    __shared__ __align__(16) float sm[11972];
    float* xs      = sm + XS_OFF;
    short* A_lds   = (short*)(sm + A_OFF);
    short* B_lds   = (short*)(sm + B_OFF);
    float* w0buf   = sm + W0_OFF;
    int*   flag    = (int*)(sm + FLAG_OFF);
    float* foldbuf = sm + FB_OFF;          // [2][20][16]
    float* dtile   = sm;                   // alias post-MFMA: [t*DT2 + (l-1)*16 + su]

    const int tid   = threadIdx.x;
    const int ttile = blockIdx.x;  // 0..31
    const int uq    = blockIdx.y;  // 0..3
    const int b     = blockIdx.z;  // 0..31
    const int t0    = ttile * TTILE;
    const int uh    = uq * 16;
    const int wv    = tid >> 6, lane = tid & 63;
    const float dtc = 2.0f / (float)(TT - 1);

    // ---- 1. async DMA: raw x tile -> xs (dword granularity, 4B-aligned safe) ----
    {
        const int   shift = (ttile > 0) ? 0 : 63;           // tile0 stages rows 0..63 at xs+63
        const int   cnt   = (ttile > 0) ? 4095 : 4032;      // 65x63 or 64x63 floats
        const float* src  = x + ((size_t)b * TT + (ttile > 0 ? t0 - 1 : 0)) * 63;
        float* dst = xs + shift;
#pragma unroll
        for (int i = 0; i < 16; ++i) {
            const int e = i * 256 + tid;
            if (e < cnt)
                __builtin_amdgcn_global_load_lds((g_char*)(src + e),
                                                 (lds_char*)(dst + e), 4, 0, 0);
        }
    }

    // ---- 2. B fragments straight from K (overlaps the DMA) ----
    // seg idx = f*40 + l*4 + q : float4 of K[f][l][uh + 4q .. +3]
#pragma unroll
    for (int i = 0; i < 10; ++i) {
        const int idx = i * 256 + tid;          // 0..2559
        const int q = idx & 3, l = (idx >> 2) % 10, f = idx / 40;
        const float4 kv = *(const float4*)(K + (size_t)(f * NL + l) * NU + uh + q * 4);
        const int reg = l * 2 + (f >> 5), qd = (f >> 3) & 3, j = f & 7;
        short* bp = B_lds + ((size_t)(reg * 64 + qd * 16 + q * 4)) * 8 + j;
        bp[0 * 8] = f2bf(kv.x);  bp[1 * 8] = f2bf(kv.y);
        bp[2 * 8] = f2bf(kv.z);  bp[3 * 8] = f2bf(kv.w);
    }
    __syncthreads();   // DMA drained + B_lds complete

    // ---- 3. A fragments: diff in fp32 from xs, round to bf16 ----
#pragma unroll
    for (int i = 0; i < 2; ++i) {
        const int e = i * 256 + tid;            // 0..511
        const int le = e & 63, reg = e >> 6;    // reg = w*2+s
        const int w = reg >> 1, s = reg & 1;
        const int t = w * 16 + (le & 15);
        const int f0 = s * 32 + (le >> 4) * 8;
        short8v v;
        if (ttile == 0 && t == 0) {
#pragma unroll
            for (int j = 0; j < 8; ++j) v[j] = 0;
        } else {
            const float* hi = xs + (t + 1) * 63;   // global row t0+t
            const float* lo = hi - 63;             // global row t0+t-1
#pragma unroll
            for (int j = 0; j < 8; ++j) {
                const int f = f0 + j;
                v[j] = f2bf(f < 63 ? hi[f] - lo[f] : dtc);
            }
        }
        *(short8v*)(A_lds + (size_t)e * 8) = v;
    }
    __syncthreads();

    // ---- 4. MFMA: wave wv computes d rows [16wv,16wv+16) x 160 cols ----
    const short8v* A8 = (const short8v*)A_lds;
    const short8v* B8 = (const short8v*)B_lds;
    const short8v a0 = A8[(wv * 2 + 0) * 64 + lane];
    const short8v a1 = A8[(wv * 2 + 1) * 64 + lane];
    float4v acc[10];
#pragma unroll
    for (int nt = 0; nt < 10; ++nt) {
        const short8v b0 = B8[(nt * 2 + 0) * 64 + lane];
        const short8v b1 = B8[(nt * 2 + 1) * 64 + lane];
        float4v z = {0.f, 0.f, 0.f, 0.f};
        z = __builtin_amdgcn_mfma_f32_16x16x32_bf16(a0, b0, z, 0, 0, 0);
        z = __builtin_amdgcn_mfma_f32_16x16x32_bf16(a1, b1, z, 0, 0, 0);
        acc[nt] = z;
    }

    // ---- 5. word (0): reduce acc[0] ----
    float s0 = acc[0][0] + acc[0][1] + acc[0][2] + acc[0][3];
    s0 += __shfl_xor(s0, 16);
    s0 += __shfl_xor(s0, 32);
    if (lane < 16) w0buf[wv * 16 + lane] = s0;
    __syncthreads();   // frag reads done -> dtile aliasing safe; w0buf visible

    // ---- 6. scatter d (l=1..9) -> dtile: col=nt*16+(lane&15), row=(lane>>4)*4+r ----
    const int qd = lane >> 4, nl = lane & 15;
#pragma unroll
    for (int nt = 1; nt < 10; ++nt)
#pragma unroll
        for (int r = 0; r < 4; ++r)
            dtile[(wv * 16 + qd * 4 + r) * DT2 + (nt - 1) * 16 + nl] = acc[nt][r];
    __syncthreads();

    // ---- 7. scan: wave = chain; lanes = 4 sub-chunks x 16 u; xor-tree fold ----
    const int sub = (tid >> 4) & 3;
    const int su  = tid & 15;
    const float* dp = dtile + su;
    const int tb = sub * 16;
    float S[10];
#pragma unroll
    for (int i = 0; i < 10; ++i) S[i] = 0.0f;

    float* Lb = L + ((size_t)(b * NTTILE + ttile) * NW) * NU + uh + su;

    if (wv == 0) {            // chain 1: l=1,2 -> col offs 0,16
        for (int t = tb; t < tb + 16; ++t) {
            const float d1 = dp[t * DT2 + 0];
            const float d2 = dp[t * DT2 + 16];
            S[2] += S[0] * d2;
            S[0] += d1;  S[1] += d2;
        }
        wave_fold<3>(S, sub, Chen1());
        if (sub == 0) { Lb[1*NU] = S[0];  Lb[2*NU] = S[1];  Lb[3*NU] = S[2]; }
    } else if (wv == 1) {     // chain 2: l=3,4,5 -> 32,48,64
        for (int t = tb; t < tb + 16; ++t) {
            const float d3 = dp[t * DT2 + 32];
            const float d4 = dp[t * DT2 + 48];
            const float d5 = dp[t * DT2 + 64];
            S[5] += S[3] * d5;
            S[3] += S[0] * d4;
            S[4] += S[1] * d5;
            S[0] += d3;  S[1] += d4;  S[2] += d5;
        }
        wave_fold<6>(S, sub, Chen2());
        if (sub == 0) {
            Lb[4*NU] = S[0];  Lb[5*NU] = S[1];  Lb[6*NU] = S[2];
            Lb[7*NU] = S[3];  Lb[8*NU] = S[4];  Lb[9*NU] = S[5];
        }
    } else if (wv == 2) {     // chain 3: l=6..9 -> 80,96,112,128
        for (int t = tb; t < tb + 16; ++t) {
            const float d6 = dp[t * DT2 + 80];
            const float d7 = dp[t * DT2 + 96];
            const float d8 = dp[t * DT2 + 112];
            const float d9 = dp[t * DT2 + 128];
            S[9] += S[7] * d9;
            S[7] += S[4] * d8;
            S[8] += S[5] * d9;
            S[4] += S[0] * d7;
            S[5] += S[1] * d8;
            S[6] += S[2] * d9;
            S[0] += d6;  S[1] += d7;  S[2] += d8;  S[3] += d9;
        }
        wave_fold<10>(S, sub, Chen3());
        if (sub == 0) {
            Lb[10*NU] = S[0]; Lb[11*NU] = S[1]; Lb[12*NU] = S[2]; Lb[13*NU] = S[3];
            Lb[14*NU] = S[4]; Lb[15*NU] = S[5]; Lb[16*NU] = S[6];
            Lb[17*NU] = S[7]; Lb[18*NU] = S[8]; Lb[19*NU] = S[9];
        }
    } else {                  // wave 3: finalize word (0)
        if (lane < 16) {
            const float w0 = w0buf[lane] + w0buf[16 + lane] + w0buf[32 + lane] + w0buf[48 + lane];
            Lb[0] = w0;
        }
    }

    // ---- 8. completion count; last block per (b,uq) folds all 32 chunks ----
    __syncthreads();   // all global word-writes issued & drained (barrier waits vmcnt)
    if (tid == 0) {
        const unsigned old = __hip_atomic_fetch_add(ctr + (b * 4 + uq), 1u,
                                                    __ATOMIC_ACQ_REL,
                                                    __HIP_MEMORY_SCOPE_AGENT);
        *flag = (int)old;
    }
    __syncthreads();
    if (*flag != NTTILE - 1) return;   // block-uniform

    // ---- 9. winner fold: wave q folds chunks [8q,8q+8); lanes = 4 grp x 16 su ----
    {
        const int q = wv, grp = (lane >> 4), fsu = lane & 15;
        const float* Lf = L + (size_t)b * NTTILE * NW * NU + uh + fsu;
        const int c0 = q * 8 + grp * 2;
        float E[NW], Bw[NW], Cw[NW];
        {
            const float* p = Lf + (size_t)c0 * NW * NU;
#pragma unroll
            for (int w = 0; w < NW; ++w) E[w] = p[w * NU];
        }
        {
            const float* p = Lf + (size_t)(c0 + 1) * NW * NU;
#pragma unroll
            for (int w = 0; w < NW; ++w) Bw[w] = p[w * NU];
            chen_combine(E, Bw, Cw);
#pragma unroll
            for (int w = 0; w < NW; ++w) E[w] = Cw[w];
        }
        wave_fold<NW>(E, grp, Chen20());   // wave q now holds fold of [8q, 8q+8)

        // 2-level tree over waves: (0∘1), (2∘3), then ∘
        if ((q == 1 || q == 3) && grp == 0) {
            float* fb = foldbuf + (q >> 1) * (NW * 16);
#pragma unroll
            for (int w = 0; w < NW; ++w) fb[w * 16 + fsu] = E[w];
        }
        __syncthreads();
        if (q == 0 || q == 2) {
            const float* fb = foldbuf + (q >> 1) * (NW * 16);
#pragma unroll
            for (int w = 0; w < NW; ++w) Bw[w] = fb[w * 16 + fsu];
            chen_combine(E, Bw, Cw);
#pragma unroll
            for (int w = 0; w < NW; ++w) E[w] = Cw[w];
        }
        __syncthreads();
        if (q == 2 && grp == 0) {
#pragma unroll
            for (int w = 0; w < NW; ++w) foldbuf[w * 16 + fsu] = E[w];
        }
        __syncthreads();
        if (q == 0) {
#pragma unroll
            for (int w = 0; w < NW; ++w) Bw[w] = foldbuf[w * 16 + fsu];
            chen_combine(E, Bw, Cw);
            if (grp == 0)
                out[b * NU + uh + fsu] = Cw[0] + Cw[3] + Cw[9] + Cw[19];
        }
    }
}

extern "C" void kernel_launch(void* const* d_in, const int* in_sizes, int n_in,
                              void* d_out, int out_size, void* d_ws, size_t ws_size,
                              hipStream_t stream) {
    const float* x = (const float*)d_in[0];   // (32, 2048, 63) fp32
    const float* K = (const float*)d_in[1];   // (64, 10, 64)  fp32
    float* out = (float*)d_out;               // (32, 64) fp32
    float* L   = (float*)d_ws;                // 5,242,880 B
    unsigned* ctr = (unsigned*)((char*)d_ws + CTR_OFF);   // 128 counters

    hipMemsetAsync(ctr, 0, 128 * sizeof(unsigned), stream);
    dim3 g1(NTTILE, 4, NB);                   // (32, 4, 32)
    k_fused<<<g1, 256, 0, stream>>>(x, K, L, ctr, out);
}

// Round 7
// 92.394 us; speedup vs baseline: 2.2225x; 2.2225x over previous
//
#include <hip/hip_runtime.h>

// Problem constants
#define TT     2048
#define NB     32
#define NL     10
#define NU     64
#define TTILE  64
#define NTTILE 32          // chunks per b (one per block after in-block fold)
#define NW     20          // iterated-sum words per (b,chunk,u)
#define DT2    145         // d-tile row stride (floats), odd -> conflict-light

// LDS float offsets (total 11,328 floats = 45,312 B -> 3 blocks/CU)
#define XS_OFF   0        // [4096]  raw x tile rows t0-1..t0+63 (or 0..63 shifted)
#define A_OFF    4096     // [2048]  A fragments (4096 bf16)
#define B_OFF    6144     // [5120]  B fragments (10240 bf16)
#define W0_OFF   11264    // [64]    word-0 partials
// dtile aliases [0, 9280) after MFMA (xs+A+low B are dead then)

typedef __attribute__((ext_vector_type(8))) short short8v;   // 8 bf16
typedef __attribute__((ext_vector_type(4))) float float4v;   // MFMA C/D
typedef __attribute__((address_space(3))) char lds_char;
typedef __attribute__((address_space(1))) const char g_char;

__device__ inline short f2bf(float f) {   // RNE float->bf16 raw bits
    unsigned u = __float_as_uint(f);
    u += 0x7fffu + ((u >> 16) & 1u);
    return (short)(u >> 16);
}

// ---- Chen composition (full 20-word alphabet), C = A(earlier) ∘ B(later) ----
// 0:(0) | 1:(1) 2:(2) 3:(12) | 4:(3) 5:(4) 6:(5) 7:(34) 8:(45) 9:(345)
// 10:(6) 11:(7) 12:(8) 13:(9) 14:(67) 15:(78) 16:(89) 17:(678) 18:(789) 19:(6789)
__device__ inline void chen_combine(const float* A, const float* B, float* C) {
    C[0]  = A[0] + B[0];
    C[1]  = A[1] + B[1];
    C[2]  = A[2] + B[2];
    C[3]  = A[3] + A[1]*B[2] + B[3];
    C[4]  = A[4] + B[4];
    C[5]  = A[5] + B[5];
    C[6]  = A[6] + B[6];
    C[7]  = A[7] + A[4]*B[5] + B[7];
    C[8]  = A[8] + A[5]*B[6] + B[8];
    C[9]  = A[9] + A[7]*B[6] + A[4]*B[8] + B[9];
    C[10] = A[10] + B[10];
    C[11] = A[11] + B[11];
    C[12] = A[12] + B[12];
    C[13] = A[13] + B[13];
    C[14] = A[14] + A[10]*B[11] + B[14];
    C[15] = A[15] + A[11]*B[12] + B[15];
    C[16] = A[16] + A[12]*B[13] + B[16];
    C[17] = A[17] + A[14]*B[12] + A[10]*B[15] + B[17];
    C[18] = A[18] + A[15]*B[13] + A[11]*B[16] + B[18];
    C[19] = A[19] + A[17]*B[13] + A[14]*B[16] + A[10]*B[18] + B[19];
}

// ---- chain-local Chen combiners ----
struct Chen1 {  // S0=(1) S1=(2) S2=(12)
    __device__ void operator()(const float* A, const float* B, float* C) const {
        C[2] = A[2] + A[0]*B[1] + B[2];
        C[0] = A[0] + B[0];  C[1] = A[1] + B[1];
    }
};
struct Chen2 {  // S0=(3) S1=(4) S2=(5) S3=(34) S4=(45) S5=(345)
    __device__ void operator()(const float* A, const float* B, float* C) const {
        C[5] = A[5] + A[3]*B[2] + A[0]*B[4] + B[5];
        C[3] = A[3] + A[0]*B[1] + B[3];
        C[4] = A[4] + A[1]*B[2] + B[4];
        C[0] = A[0] + B[0];  C[1] = A[1] + B[1];  C[2] = A[2] + B[2];
    }
};
struct Chen3 {  // S0..3=(6)(7)(8)(9) S4=(67) S5=(78) S6=(89) S7=(678) S8=(789) S9=(6789)
    __device__ void operator()(const float* A, const float* B, float* C) const {
        C[9] = A[9] + A[7]*B[3] + A[4]*B[6] + A[0]*B[8] + B[9];
        C[7] = A[7] + A[4]*B[2] + A[0]*B[5] + B[7];
        C[8] = A[8] + A[5]*B[3] + A[1]*B[6] + B[8];
        C[4] = A[4] + A[0]*B[1] + B[4];
        C[5] = A[5] + A[1]*B[2] + B[5];
        C[6] = A[6] + A[2]*B[3] + B[6];
        C[0] = A[0] + B[0];  C[1] = A[1] + B[1];
        C[2] = A[2] + B[2];  C[3] = A[3] + B[3];
    }
};

// Cross-lane fold of 4 t-ordered groups (grp = lane>>4) via xor-16/32 tree.
template <int N, typename CH>
__device__ inline void wave_fold(float* S, int grp, CH chen) {
    float O[N], A[N], Bv[N], C[N];
#pragma unroll
    for (int w = 0; w < N; ++w) O[w] = __shfl_xor(S[w], 16);
    {
        const bool e = (grp & 1) == 0;
#pragma unroll
        for (int w = 0; w < N; ++w) { A[w] = e ? S[w] : O[w]; Bv[w] = e ? O[w] : S[w]; }
        chen(A, Bv, C);
    }
#pragma unroll
    for (int w = 0; w < N; ++w) O[w] = __shfl_xor(C[w], 32);
    {
        const bool e = (grp & 2) == 0;
#pragma unroll
        for (int w = 0; w < N; ++w) { A[w] = e ? C[w] : O[w]; Bv[w] = e ? O[w] : C[w]; }
        chen(A, Bv, S);
    }
}

// Fused kernel: DMA x-tile -> LDS, build A/B bf16 fragments in-kernel, MFMA
// d = dX*K, chain scans + in-block Chen fold -> 20 words per (b,chunk,uq).
__global__ __launch_bounds__(256, 3)
void k_fused(const float* __restrict__ x, const float* __restrict__ K,
             float* __restrict__ L) {
    __shared__ __align__(16) float sm[11328];
    float* xs    = sm + XS_OFF;
    short* A_lds = (short*)(sm + A_OFF);
    short* B_lds = (short*)(sm + B_OFF);
    float* w0buf = sm + W0_OFF;
    float* dtile = sm;                   // alias post-MFMA: [t*DT2 + (l-1)*16 + su]

    const int tid   = threadIdx.x;
    const int ttile = blockIdx.x;  // 0..31
    const int uq    = blockIdx.y;  // 0..3
    const int b     = blockIdx.z;  // 0..31
    const int t0    = ttile * TTILE;
    const int uh    = uq * 16;
    const int wv    = tid >> 6, lane = tid & 63;
    const float dtc = 2.0f / (float)(TT - 1);

    // ---- 1. async DMA: raw x tile -> xs (dword width; rows are 4B-aligned only) ----
    {
        const int   shift = (ttile > 0) ? 0 : 63;        // tile0: rows 0..63 at xs+63
        const int   cnt   = (ttile > 0) ? 4095 : 4032;   // floats staged
        const float* src  = x + ((size_t)b * TT + (ttile > 0 ? t0 - 1 : 0)) * 63;
        float* dst = xs + shift;
#pragma unroll
        for (int i = 0; i < 16; ++i) {
            const int e = i * 256 + tid;
            if (e < cnt)
                __builtin_amdgcn_global_load_lds((g_char*)(src + e),
                                                 (lds_char*)(dst + e), 4, 0, 0);
        }
    }

    // ---- 2. B fragments: per-thread strided K loads -> ONE short8v write each ----
    // short8v idx in [0,1280): lane' = idx&63, reg = idx>>6 (= l*2+s)
    // element j of (reg, lane') = K[f = s*32 + (lane'>>4)*8 + j][l][uh + (lane'&15)]
#pragma unroll
    for (int i = 0; i < 5; ++i) {
        const int idx = i * 256 + tid;
        const int ln = idx & 63, r20 = idx >> 6;
        const int l = r20 >> 1, s = r20 & 1;
        const int f0 = s * 32 + (ln >> 4) * 8;
        const int u = uh + (ln & 15);
        const float* kp = K + (size_t)f0 * (NL * NU) + l * NU + u;
        short8v v;
#pragma unroll
        for (int j = 0; j < 8; ++j) v[j] = f2bf(kp[(size_t)j * (NL * NU)]);
        *(short8v*)(B_lds + (size_t)idx * 8) = v;
    }
    __syncthreads();   // DMA drained + B_lds complete

    // ---- 3. A fragments: diff in fp32 from xs, round to bf16 ----
#pragma unroll
    for (int i = 0; i < 2; ++i) {
        const int e = i * 256 + tid;            // 0..511
        const int le = e & 63, reg = e >> 6;    // reg = w*2+s
        const int w = reg >> 1, s = reg & 1;
        const int t = w * 16 + (le & 15);
        const int f0 = s * 32 + (le >> 4) * 8;
        short8v v;
        if (ttile == 0 && t == 0) {
#pragma unroll
            for (int j = 0; j < 8; ++j) v[j] = 0;
        } else {
            const float* hi = xs + (t + 1) * 63;   // global row t0+t
            const float* lo = hi - 63;             // global row t0+t-1
#pragma unroll
            for (int j = 0; j < 8; ++j) {
                const int f = f0 + j;
                v[j] = f2bf(f < 63 ? hi[f] - lo[f] : dtc);
            }
        }
        *(short8v*)(A_lds + (size_t)e * 8) = v;
    }
    __syncthreads();

    // ---- 4. MFMA: wave wv computes d rows [16wv,16wv+16) x 160 cols ----
    const short8v* A8 = (const short8v*)A_lds;
    const short8v* B8 = (const short8v*)B_lds;
    const short8v a0 = A8[(wv * 2 + 0) * 64 + lane];
    const short8v a1 = A8[(wv * 2 + 1) * 64 + lane];
    float4v acc[10];
#pragma unroll
    for (int nt = 0; nt < 10; ++nt) {
        const short8v b0 = B8[(nt * 2 + 0) * 64 + lane];
        const short8v b1 = B8[(nt * 2 + 1) * 64 + lane];
        float4v z = {0.f, 0.f, 0.f, 0.f};
        z = __builtin_amdgcn_mfma_f32_16x16x32_bf16(a0, b0, z, 0, 0, 0);
        z = __builtin_amdgcn_mfma_f32_16x16x32_bf16(a1, b1, z, 0, 0, 0);
        acc[nt] = z;
    }

    // ---- 5. word (0): reduce acc[0] ----
    float s0 = acc[0][0] + acc[0][1] + acc[0][2] + acc[0][3];
    s0 += __shfl_xor(s0, 16);
    s0 += __shfl_xor(s0, 32);
    if (lane < 16) w0buf[wv * 16 + lane] = s0;
    __syncthreads();   // frag reads done -> dtile aliasing safe; w0buf visible

    // ---- 6. scatter d (l=1..9) -> dtile: col=nt*16+(lane&15), row=(lane>>4)*4+r ----
    const int qd = lane >> 4, nl = lane & 15;
#pragma unroll
    for (int nt = 1; nt < 10; ++nt)
#pragma unroll
        for (int r = 0; r < 4; ++r)
            dtile[(wv * 16 + qd * 4 + r) * DT2 + (nt - 1) * 16 + nl] = acc[nt][r];
    __syncthreads();

    // ---- 7. scan: wave = chain; lanes = 4 sub-chunks x 16 u; xor-tree fold ----
    const int sub = (tid >> 4) & 3;
    const int su  = tid & 15;
    const float* dp = dtile + su;
    const int tb = sub * 16;
    float S[10];
#pragma unroll
    for (int i = 0; i < 10; ++i) S[i] = 0.0f;

    float* Lb = L + ((size_t)(b * NTTILE + ttile) * NW) * NU + uh + su;

    if (wv == 0) {            // chain 1: l=1,2 -> col offs 0,16
        for (int t = tb; t < tb + 16; ++t) {
            const float d1 = dp[t * DT2 + 0];
            const float d2 = dp[t * DT2 + 16];
            S[2] += S[0] * d2;
            S[0] += d1;  S[1] += d2;
        }
        wave_fold<3>(S, sub, Chen1());
        if (sub == 0) { Lb[1*NU] = S[0];  Lb[2*NU] = S[1];  Lb[3*NU] = S[2]; }
    } else if (wv == 1) {     // chain 2: l=3,4,5 -> 32,48,64
        for (int t = tb; t < tb + 16; ++t) {
            const float d3 = dp[t * DT2 + 32];
            const float d4 = dp[t * DT2 + 48];
            const float d5 = dp[t * DT2 + 64];
            S[5] += S[3] * d5;
            S[3] += S[0] * d4;
            S[4] += S[1] * d5;
            S[0] += d3;  S[1] += d4;  S[2] += d5;
        }
        wave_fold<6>(S, sub, Chen2());
        if (sub == 0) {
            Lb[4*NU] = S[0];  Lb[5*NU] = S[1];  Lb[6*NU] = S[2];
            Lb[7*NU] = S[3];  Lb[8*NU] = S[4];  Lb[9*NU] = S[5];
        }
    } else if (wv == 2) {     // chain 3: l=6..9 -> 80,96,112,128
        for (int t = tb; t < tb + 16; ++t) {
            const float d6 = dp[t * DT2 + 80];
            const float d7 = dp[t * DT2 + 96];
            const float d8 = dp[t * DT2 + 112];
            const float d9 = dp[t * DT2 + 128];
            S[9] += S[7] * d9;
            S[7] += S[4] * d8;
            S[8] += S[5] * d9;
            S[4] += S[0] * d7;
            S[5] += S[1] * d8;
            S[6] += S[2] * d9;
            S[0] += d6;  S[1] += d7;  S[2] += d8;  S[3] += d9;
        }
        wave_fold<10>(S, sub, Chen3());
        if (sub == 0) {
            Lb[10*NU] = S[0]; Lb[11*NU] = S[1]; Lb[12*NU] = S[2]; Lb[13*NU] = S[3];
            Lb[14*NU] = S[4]; Lb[15*NU] = S[5]; Lb[16*NU] = S[6];
            Lb[17*NU] = S[7]; Lb[18*NU] = S[8]; Lb[19*NU] = S[9];
        }
    } else {                  // wave 3: finalize word (0)
        if (lane < 16) {
            const float w0 = w0buf[lane] + w0buf[16 + lane] + w0buf[32 + lane] + w0buf[48 + lane];
            Lb[0] = w0;
        }
    }
}

// Kernel 2: fold 32 chunks per b. 8 waves x 4 serial chunks + 3-level LDS tree.
__global__ __launch_bounds__(512)
void k_fold(const float* __restrict__ L, float* __restrict__ out) {
    __shared__ float buf[4][NW][NU];    // 20,480 B
    const int b = blockIdx.x;
    const int u = threadIdx.x & 63;
    const int q = threadIdx.x >> 6;     // 0..7
    const float* Lb = L + (size_t)b * NTTILE * NW * NU + u;

    float E[NW];
    {
        const float* p = Lb + (size_t)(q * 4) * NW * NU;
#pragma unroll
        for (int w = 0; w < NW; ++w) E[w] = p[w * NU];
    }
    for (int c = q * 4 + 1; c < q * 4 + 4; ++c) {
        const float* p = Lb + (size_t)c * NW * NU;
        float Bw[NW], Cw[NW];
#pragma unroll
        for (int w = 0; w < NW; ++w) Bw[w] = p[w * NU];
        chen_combine(E, Bw, Cw);
#pragma unroll
        for (int w = 0; w < NW; ++w) E[w] = Cw[w];
    }

#pragma unroll
    for (int lvl = 0; lvl < 3; ++lvl) {
        const int step = 1 << lvl;
        const bool active = (q & (step - 1)) == 0;
        const bool writer = active && ((q >> lvl) & 1);
        if (writer) {
            const int idx = (q - step) >> (lvl + 1);
#pragma unroll
            for (int w = 0; w < NW; ++w) buf[idx][w][u] = E[w];
        }
        __syncthreads();
        if (active && !writer) {
            const int idx = q >> (lvl + 1);
            float Bw[NW], Cw[NW];
#pragma unroll
            for (int w = 0; w < NW; ++w) Bw[w] = buf[idx][w][u];
            chen_combine(E, Bw, Cw);
#pragma unroll
            for (int w = 0; w < NW; ++w) E[w] = Cw[w];
        }
        __syncthreads();
    }
    if (q == 0) out[b * NU + u] = E[0] + E[3] + E[9] + E[19];
}

extern "C" void kernel_launch(void* const* d_in, const int* in_sizes, int n_in,
                              void* d_out, int out_size, void* d_ws, size_t ws_size,
                              hipStream_t stream) {
    const float* x = (const float*)d_in[0];   // (32, 2048, 63) fp32
    const float* K = (const float*)d_in[1];   // (64, 10, 64)  fp32
    float* out = (float*)d_out;               // (32, 64) fp32
    float* L   = (float*)d_ws;                // 5,242,880 B

    dim3 g1(NTTILE, 4, NB);                   // (32, 4, 32)
    k_fused<<<g1, 256, 0, stream>>>(x, K, L);
    k_fold<<<NB, 512, 0, stream>>>(L, out);
}

// Round 8
// 90.606 us; speedup vs baseline: 2.2664x; 1.0197x over previous
//
#include <hip/hip_runtime.h>

// Problem constants
#define TT     2048
#define NB     32
#define NL     10
#define NU     64
#define TTILE  64
#define NTTILE 32          // chunks per b
#define NW     20          // iterated-sum words per (b,chunk,u)
#define DT3    145         // d-tile row stride (cols 144 = l=1..9 x 16; odd)

// LDS float offsets. Staging: A [0,2048), B [2048,7168).
// dtile aliases [0,9425) post-MFMA: 65 rows (M[t0-1 .. t0+63]) x 145.
#define A_OFF    0
#define B_OFF    2048
#define W0_OFF   9428      // [32] word-0 endpoints (boundary M0 / row-63 M0)
#define SM_FLOATS 9460     // 37,840 B -> 4 blocks/CU

typedef __attribute__((ext_vector_type(8))) short short8v;   // 8 bf16
typedef __attribute__((ext_vector_type(4))) float float4v;   // MFMA C/D

__device__ inline short f2bf(float f) {   // RNE float->bf16 raw bits
    unsigned u = __float_as_uint(f);
    u += 0x7fffu + ((u >> 16) & 1u);
    return (short)(u >> 16);
}

// ---- Chen composition (full 20-word alphabet), C = A(earlier) ∘ B(later) ----
// 0:(0) | 1:(1) 2:(2) 3:(12) | 4:(3) 5:(4) 6:(5) 7:(34) 8:(45) 9:(345)
// 10:(6) 11:(7) 12:(8) 13:(9) 14:(67) 15:(78) 16:(89) 17:(678) 18:(789) 19:(6789)
__device__ inline void chen_combine(const float* A, const float* B, float* C) {
    C[0]  = A[0] + B[0];
    C[1]  = A[1] + B[1];
    C[2]  = A[2] + B[2];
    C[3]  = A[3] + A[1]*B[2] + B[3];
    C[4]  = A[4] + B[4];
    C[5]  = A[5] + B[5];
    C[6]  = A[6] + B[6];
    C[7]  = A[7] + A[4]*B[5] + B[7];
    C[8]  = A[8] + A[5]*B[6] + B[8];
    C[9]  = A[9] + A[7]*B[6] + A[4]*B[8] + B[9];
    C[10] = A[10] + B[10];
    C[11] = A[11] + B[11];
    C[12] = A[12] + B[12];
    C[13] = A[13] + B[13];
    C[14] = A[14] + A[10]*B[11] + B[14];
    C[15] = A[15] + A[11]*B[12] + B[15];
    C[16] = A[16] + A[12]*B[13] + B[16];
    C[17] = A[17] + A[14]*B[12] + A[10]*B[15] + B[17];
    C[18] = A[18] + A[15]*B[13] + A[11]*B[16] + B[18];
    C[19] = A[19] + A[17]*B[13] + A[14]*B[16] + A[10]*B[18] + B[19];
}

// ---- chain-local Chen combiners ----
struct Chen1 {  // S0=(1) S1=(2) S2=(12)
    __device__ void operator()(const float* A, const float* B, float* C) const {
        C[2] = A[2] + A[0]*B[1] + B[2];
        C[0] = A[0] + B[0];  C[1] = A[1] + B[1];
    }
};
struct Chen2 {  // S0=(3) S1=(4) S2=(5) S3=(34) S4=(45) S5=(345)
    __device__ void operator()(const float* A, const float* B, float* C) const {
        C[5] = A[5] + A[3]*B[2] + A[0]*B[4] + B[5];
        C[3] = A[3] + A[0]*B[1] + B[3];
        C[4] = A[4] + A[1]*B[2] + B[4];
        C[0] = A[0] + B[0];  C[1] = A[1] + B[1];  C[2] = A[2] + B[2];
    }
};
struct Chen3 {  // S0..3=(6)(7)(8)(9) S4=(67) S5=(78) S6=(89) S7=(678) S8=(789) S9=(6789)
    __device__ void operator()(const float* A, const float* B, float* C) const {
        C[9] = A[9] + A[7]*B[3] + A[4]*B[6] + A[0]*B[8] + B[9];
        C[7] = A[7] + A[4]*B[2] + A[0]*B[5] + B[7];
        C[8] = A[8] + A[5]*B[3] + A[1]*B[6] + B[8];
        C[4] = A[4] + A[0]*B[1] + B[4];
        C[5] = A[5] + A[1]*B[2] + B[5];
        C[6] = A[6] + A[2]*B[3] + B[6];
        C[0] = A[0] + B[0];  C[1] = A[1] + B[1];
        C[2] = A[2] + B[2];  C[3] = A[3] + B[3];
    }
};

// Cross-lane fold of 4 t-ordered groups (grp = lane>>4) via xor-16/32 tree.
template <int N, typename CH>
__device__ inline void wave_fold(float* S, int grp, CH chen) {
    float O[N], A[N], Bv[N], C[N];
#pragma unroll
    for (int w = 0; w < N; ++w) O[w] = __shfl_xor(S[w], 16);
    {
        const bool e = (grp & 1) == 0;
#pragma unroll
        for (int w = 0; w < N; ++w) { A[w] = e ? S[w] : O[w]; Bv[w] = e ? O[w] : S[w]; }
        chen(A, Bv, C);
    }
#pragma unroll
    for (int w = 0; w < N; ++w) O[w] = __shfl_xor(C[w], 32);
    {
        const bool e = (grp & 2) == 0;
#pragma unroll
        for (int w = 0; w < N; ++w) { A[w] = e ? C[w] : O[w]; Bv[w] = e ? O[w] : C[w]; }
        chen(A, Bv, S);
    }
}

// Fused kernel (diff-after-GEMM): build A = bf16(X rows) and B = bf16(K) frags,
// MFMA M = X*K (wave 3 also computes the boundary row M[t0-1]), scatter M to
// LDS, scan chains on d[t] = M[t]-M[t-1], in-block Chen fold -> 20 words.
__global__ __launch_bounds__(256, 4)
void k_fused(const float* __restrict__ x, const float* __restrict__ K,
             float* __restrict__ L) {
    __shared__ __align__(16) float sm[SM_FLOATS];
    short* A_lds = (short*)(sm + A_OFF);   // [8][64][8] bf16
    short* B_lds = (short*)(sm + B_OFF);   // [20][64][8] bf16
    float* w0buf = sm + W0_OFF;            // [32]
    float* dtile = sm;                     // alias post-MFMA: [r*145 + (l-1)*16 + su]

    const int tid   = threadIdx.x;
    const int ttile = blockIdx.x;  // 0..31
    const int uq    = blockIdx.y;  // 0..3
    const int b     = blockIdx.z;  // 0..31
    const int t0    = ttile * TTILE;
    const int uh    = uq * 16;
    const int wv    = tid >> 6, lane = tid & 63;
    const float dtc = 2.0f / (float)(TT - 1);

    // ---- 1a. B fragments: strided K loads -> one short8v write each ----
    // reg = l*2+s; element j of (reg,ln) = K[f = s*32+(ln>>4)*8+j][l][uh+(ln&15)]
#pragma unroll
    for (int i = 0; i < 5; ++i) {
        const int idx = i * 256 + tid;
        const int ln = idx & 63, r20 = idx >> 6;
        const int l = r20 >> 1, s = r20 & 1;
        const int f0 = s * 32 + (ln >> 4) * 8;
        const int u = uh + (ln & 15);
        const float* kp = K + (size_t)f0 * (NL * NU) + l * NU + u;
        short8v v;
#pragma unroll
        for (int j = 0; j < 8; ++j) v[j] = f2bf(kp[(size_t)j * (NL * NU)]);
        *(short8v*)(B_lds + (size_t)idx * 8) = v;
    }

    // ---- 1b. A fragments: bf16(X) straight from global (incl. time channel) ----
#pragma unroll
    for (int i = 0; i < 2; ++i) {
        const int e = i * 256 + tid;            // 0..511
        const int le = e & 63, reg = e >> 6;    // reg = w*2+s
        const int w = reg >> 1, s = reg & 1;
        const int t = w * 16 + (le & 15);
        const int f0 = s * 32 + (le >> 4) * 8;
        const int tg = t0 + t;
        const float* xp = x + (size_t)(b * TT + tg) * 63;
        const float tv = (float)tg * dtc - 1.0f;
        short8v v;
#pragma unroll
        for (int j = 0; j < 8; ++j) {
            const int f = f0 + j;
            v[j] = f2bf(f < 63 ? xp[f] : tv);
        }
        *(short8v*)(A_lds + (size_t)e * 8) = v;
    }

    // ---- 1c. boundary A-fragment (wave 3): row 0 = X[max(t0-1,0)], rest 0 ----
    short8v ab0 = {0,0,0,0,0,0,0,0}, ab1 = {0,0,0,0,0,0,0,0};
    if (wv == 3 && (lane & 15) == 0) {
        const int tp = (ttile > 0) ? t0 - 1 : 0;
        const float* xp = x + (size_t)(b * TT + tp) * 63;
        const float tv = (float)tp * dtc - 1.0f;
        const int qd0 = lane >> 4;
#pragma unroll
        for (int j = 0; j < 8; ++j) {
            const int fa = qd0 * 8 + j;          // s=0 half
            const int fb = 32 + qd0 * 8 + j;     // s=1 half
            ab0[j] = f2bf(xp[fa]);               // fa < 32 always valid
            ab1[j] = f2bf(fb < 63 ? xp[fb] : tv);
        }
    }
    __syncthreads();

    // ---- 2. MFMA: wave wv computes M rows [16wv,16wv+16) x 160 cols ----
    const short8v* A8 = (const short8v*)A_lds;
    const short8v* B8 = (const short8v*)B_lds;
    const short8v a0 = A8[(wv * 2 + 0) * 64 + lane];
    const short8v a1 = A8[(wv * 2 + 1) * 64 + lane];
    float4v acc[10];
    float bnd[10];
#pragma unroll
    for (int nt = 0; nt < 10; ++nt) {
        const short8v b0 = B8[(nt * 2 + 0) * 64 + lane];
        const short8v b1 = B8[(nt * 2 + 1) * 64 + lane];
        float4v z = {0.f, 0.f, 0.f, 0.f};
        z = __builtin_amdgcn_mfma_f32_16x16x32_bf16(a0, b0, z, 0, 0, 0);
        z = __builtin_amdgcn_mfma_f32_16x16x32_bf16(a1, b1, z, 0, 0, 0);
        acc[nt] = z;
        if (wv == 3) {   // boundary row: only C row 0 (reg 0, lanes 0-15) is used
            float4v zb = {0.f, 0.f, 0.f, 0.f};
            zb = __builtin_amdgcn_mfma_f32_16x16x32_bf16(ab0, b0, zb, 0, 0, 0);
            zb = __builtin_amdgcn_mfma_f32_16x16x32_bf16(ab1, b1, zb, 0, 0, 0);
            bnd[nt] = zb[0];
        }
    }
    __syncthreads();   // frag reads done -> dtile aliasing safe

    // ---- 3. scatter M -> dtile rows 1..64; wave 3 adds row 0 + word-0 endpoints ----
    const int qd = lane >> 4, nl = lane & 15;
#pragma unroll
    for (int nt = 1; nt < 10; ++nt)
#pragma unroll
        for (int r = 0; r < 4; ++r)
            dtile[(wv * 16 + qd * 4 + r + 1) * DT3 + (nt - 1) * 16 + nl] = acc[nt][r];
    if (wv == 3) {
        if (qd == 0) {           // lanes 0-15: boundary row (dtile row 0)
#pragma unroll
            for (int nt = 1; nt < 10; ++nt)
                dtile[(nt - 1) * 16 + nl] = bnd[nt];
            w0buf[nl] = bnd[0];                  // M[t0-1][0][u]
        }
        if (lane >= 48)          // row 63 = 48 + 3*4 + 3 (qd=3, reg 3)
            w0buf[16 + (lane - 48)] = acc[0][3]; // M[t0+63][0][u]
    }
    __syncthreads();

    // ---- 4. scan: wave = chain; lanes = 4 sub-chunks x 16 u; d = M[t]-M[t-1] ----
    const int sub = (tid >> 4) & 3;
    const int su  = tid & 15;
    const float* dp = dtile + su;
    const int tb = sub * 16;                     // dtile rows tb..tb+16
    float S[10];
#pragma unroll
    for (int i = 0; i < 10; ++i) S[i] = 0.0f;

    float* Lb = L + ((size_t)(b * NTTILE + ttile) * NW) * NU + uh + su;

    if (wv == 0) {            // chain 1: l=1,2 -> col offs 0,16
        float m1 = dp[tb * DT3 + 0], m2 = dp[tb * DT3 + 16];
        for (int r = tb + 1; r <= tb + 16; ++r) {
            const float n1 = dp[r * DT3 + 0];
            const float n2 = dp[r * DT3 + 16];
            const float d1 = n1 - m1, d2 = n2 - m2;
            m1 = n1;  m2 = n2;
            S[2] += S[0] * d2;
            S[0] += d1;  S[1] += d2;
        }
        wave_fold<3>(S, sub, Chen1());
        if (sub == 0) { Lb[1*NU] = S[0];  Lb[2*NU] = S[1];  Lb[3*NU] = S[2]; }
    } else if (wv == 1) {     // chain 2: l=3,4,5 -> 32,48,64
        float m3 = dp[tb * DT3 + 32], m4 = dp[tb * DT3 + 48], m5 = dp[tb * DT3 + 64];
        for (int r = tb + 1; r <= tb + 16; ++r) {
            const float n3 = dp[r * DT3 + 32];
            const float n4 = dp[r * DT3 + 48];
            const float n5 = dp[r * DT3 + 64];
            const float d3 = n3 - m3, d4 = n4 - m4, d5 = n5 - m5;
            m3 = n3;  m4 = n4;  m5 = n5;
            S[5] += S[3] * d5;
            S[3] += S[0] * d4;
            S[4] += S[1] * d5;
            S[0] += d3;  S[1] += d4;  S[2] += d5;
        }
        wave_fold<6>(S, sub, Chen2());
        if (sub == 0) {
            Lb[4*NU] = S[0];  Lb[5*NU] = S[1];  Lb[6*NU] = S[2];
            Lb[7*NU] = S[3];  Lb[8*NU] = S[4];  Lb[9*NU] = S[5];
        }
    } else if (wv == 2) {     // chain 3: l=6..9 -> 80,96,112,128
        float m6 = dp[tb * DT3 + 80],  m7 = dp[tb * DT3 + 96];
        float m8 = dp[tb * DT3 + 112], m9 = dp[tb * DT3 + 128];
        for (int r = tb + 1; r <= tb + 16; ++r) {
            const float n6 = dp[r * DT3 + 80];
            const float n7 = dp[r * DT3 + 96];
            const float n8 = dp[r * DT3 + 112];
            const float n9 = dp[r * DT3 + 128];
            const float d6 = n6 - m6, d7 = n7 - m7, d8 = n8 - m8, d9 = n9 - m9;
            m6 = n6;  m7 = n7;  m8 = n8;  m9 = n9;
            S[9] += S[7] * d9;
            S[7] += S[4] * d8;
            S[8] += S[5] * d9;
            S[4] += S[0] * d7;
            S[5] += S[1] * d8;
            S[6] += S[2] * d9;
            S[0] += d6;  S[1] += d7;  S[2] += d8;  S[3] += d9;
        }
        wave_fold<10>(S, sub, Chen3());
        if (sub == 0) {
            Lb[10*NU] = S[0]; Lb[11*NU] = S[1]; Lb[12*NU] = S[2]; Lb[13*NU] = S[3];
            Lb[14*NU] = S[4]; Lb[15*NU] = S[5]; Lb[16*NU] = S[6];
            Lb[17*NU] = S[7]; Lb[18*NU] = S[8]; Lb[19*NU] = S[9];
        }
    } else {                  // wave 3: word (0) telescopes to row63 - boundary
        if (lane < 16)
            Lb[0] = w0buf[16 + lane] - w0buf[lane];
    }
}

// Kernel 2: fold 32 chunks per b. 8 waves x 4 serial chunks + 3-level LDS tree.
__global__ __launch_bounds__(512)
void k_fold(const float* __restrict__ L, float* __restrict__ out) {
    __shared__ float buf[4][NW][NU];    // 20,480 B
    const int b = blockIdx.x;
    const int u = threadIdx.x & 63;
    const int q = threadIdx.x >> 6;     // 0..7
    const float* Lb = L + (size_t)b * NTTILE * NW * NU + u;

    float E[NW];
    {
        const float* p = Lb + (size_t)(q * 4) * NW * NU;
#pragma unroll
        for (int w = 0; w < NW; ++w) E[w] = p[w * NU];
    }
    for (int c = q * 4 + 1; c < q * 4 + 4; ++c) {
        const float* p = Lb + (size_t)c * NW * NU;
        float Bw[NW], Cw[NW];
#pragma unroll
        for (int w = 0; w < NW; ++w) Bw[w] = p[w * NU];
        chen_combine(E, Bw, Cw);
#pragma unroll
        for (int w = 0; w < NW; ++w) E[w] = Cw[w];
    }

#pragma unroll
    for (int lvl = 0; lvl < 3; ++lvl) {
        const int step = 1 << lvl;
        const bool active = (q & (step - 1)) == 0;
        const bool writer = active && ((q >> lvl) & 1);
        if (writer) {
            const int idx = (q - step) >> (lvl + 1);
#pragma unroll
            for (int w = 0; w < NW; ++w) buf[idx][w][u] = E[w];
        }
        __syncthreads();
        if (active && !writer) {
            const int idx = q >> (lvl + 1);
            float Bw[NW], Cw[NW];
#pragma unroll
            for (int w = 0; w < NW; ++w) Bw[w] = buf[idx][w][u];
            chen_combine(E, Bw, Cw);
#pragma unroll
            for (int w = 0; w < NW; ++w) E[w] = Cw[w];
        }
        __syncthreads();
    }
    if (q == 0) out[b * NU + u] = E[0] + E[3] + E[9] + E[19];
}

extern "C" void kernel_launch(void* const* d_in, const int* in_sizes, int n_in,
                              void* d_out, int out_size, void* d_ws, size_t ws_size,
                              hipStream_t stream) {
    const float* x = (const float*)d_in[0];   // (32, 2048, 63) fp32
    const float* K = (const float*)d_in[1];   // (64, 10, 64)  fp32
    float* out = (float*)d_out;               // (32, 64) fp32
    float* L   = (float*)d_ws;                // 5,242,880 B

    dim3 g1(NTTILE, 4, NB);                   // (32, 4, 32)
    k_fused<<<g1, 256, 0, stream>>>(x, K, L);
    k_fold<<<NB, 512, 0, stream>>>(L, out);
}